// Round 5
// baseline (1914.828 us; speedup 1.0000x reference)
//
#include <hip/hip_runtime.h>

#define B_ 64
#define D_ 512
#define N_ 1200
#define K_ 64
#define PT 32            // pixels per tile
#define NTILES 38        // ceil(1200/32); last tile has 16 valid pixels

__device__ __forceinline__ float bf2f(unsigned short u) {
  union { unsigned int i; float f; } v; v.i = ((unsigned int)u) << 16; return v.f;
}
__device__ __forceinline__ unsigned short f2bf(float f) {
  unsigned int u = __float_as_uint(f);
  u += 0x7FFFu + ((u >> 16) & 1u);   // round-to-nearest-even
  return (unsigned short)(u >> 16);
}

// ONE fused kernel, ZERO workspace. grid 256: id = kq*64 + b.
// Block (b,kq) owns vlad rows k in [16*kq, 16*kq+16); recomputes all-64
// logits per pixel (softmax couples K) -- 4x logit redundancy, accepted.
// Thread roles: px = t&31 (pixel in tile), kg = t>>5 (8 logits rows each);
// vlad phase: thread owns d0 = 2t for all 16 rows (32 fp32 accumulators).
// OUTPUT: fp32 (reference's output dtype) -- the ONLY change vs round 4.
__global__ __launch_bounds__(256) void k_fused(
    const float* __restrict__ x, const float* __restrict__ w,
    const float* __restrict__ cent, float* __restrict__ out)
{
  const int id = blockIdx.x;
  const int kq = id >> 6;          // 0..3
  const int b  = id & 63;
  const int t  = threadIdx.x;
  const int px = t & 31;
  const int kg = t >> 5;           // 0..7 -> global k = kg*8 + j
  const bool own = (kg >> 1) == kq; // this thread's 8 k's fall in block's 16 rows
  const int khbase = (kg & 1) * 8;  // local row base when own

  __shared__ unsigned short xs[PT][514]; // bf16 x-tile [px][d]; 257 4B-words/row (odd -> conflict-free)
  __shared__ float ls[K_][33];           // normalized logits [k][px]
  __shared__ float a_s[16][34];          // own rows: a * invn
  __shared__ float araw[16][34];         // own rows: raw a (for asum)
  __shared__ float asums[16];
  __shared__ float part[16][4];
  __shared__ float scale_s[16];

  if (t < 16) asums[t] = 0.f;

  float acc[32];
#pragma unroll
  for (int i = 0; i < 32; ++i) acc[i] = 0.f;

  const float* xb = x + (size_t)b * D_ * N_;

  for (int tile = 0; tile < NTILES; ++tile) {
    const int n0 = tile * PT;
    // ---- stage x-tile (bf16): row=t&31 (pixel), chunk=t>>5 (64 d's) ----
    {
      const int row = t & 31, chunk = t >> 5;
      const int n = n0 + row;
      const int nc = (n < N_) ? n : (N_ - 1);   // clamp; masked via a=0 later
      const float* xp = xb + (size_t)(chunk * 64) * N_ + nc;
#pragma unroll
      for (int i = 0; i < 64; ++i)
        xs[row][chunk * 64 + i] = f2bf(xp[(size_t)i * N_]);
    }
    __syncthreads();
    // ---- logits: 8 dot-products over d from LDS row px ----
    float invn;
    {
      const ushort2* xr = (const ushort2*)xs[px];
      float lg0=0.f,lg1=0.f,lg2=0.f,lg3=0.f,lg4=0.f,lg5=0.f,lg6=0.f,lg7=0.f;
      float nsq = 0.f;
      const float* wbase = w + (size_t)(kg * 8) * D_;
      for (int du = 0; du < D_ / 4; ++du) {   // d = 4*du .. 4*du+3
        const ushort2 p0 = xr[2 * du], p1 = xr[2 * du + 1];
        const float x0 = bf2f(p0.x), x1 = bf2f(p0.y), x2 = bf2f(p1.x), x3 = bf2f(p1.y);
        nsq += x0 * x0 + x1 * x1 + x2 * x2 + x3 * x3;
        const float4 w0 = *(const float4*)(wbase + 0 * D_ + 4 * du);
        const float4 w1 = *(const float4*)(wbase + 1 * D_ + 4 * du);
        const float4 w2 = *(const float4*)(wbase + 2 * D_ + 4 * du);
        const float4 w3 = *(const float4*)(wbase + 3 * D_ + 4 * du);
        const float4 w4 = *(const float4*)(wbase + 4 * D_ + 4 * du);
        const float4 w5 = *(const float4*)(wbase + 5 * D_ + 4 * du);
        const float4 w6 = *(const float4*)(wbase + 6 * D_ + 4 * du);
        const float4 w7 = *(const float4*)(wbase + 7 * D_ + 4 * du);
        lg0 = fmaf(x0,w0.x,fmaf(x1,w0.y,fmaf(x2,w0.z,fmaf(x3,w0.w,lg0))));
        lg1 = fmaf(x0,w1.x,fmaf(x1,w1.y,fmaf(x2,w1.z,fmaf(x3,w1.w,lg1))));
        lg2 = fmaf(x0,w2.x,fmaf(x1,w2.y,fmaf(x2,w2.z,fmaf(x3,w2.w,lg2))));
        lg3 = fmaf(x0,w3.x,fmaf(x1,w3.y,fmaf(x2,w3.z,fmaf(x3,w3.w,lg3))));
        lg4 = fmaf(x0,w4.x,fmaf(x1,w4.y,fmaf(x2,w4.z,fmaf(x3,w4.w,lg4))));
        lg5 = fmaf(x0,w5.x,fmaf(x1,w5.y,fmaf(x2,w5.z,fmaf(x3,w5.w,lg5))));
        lg6 = fmaf(x0,w6.x,fmaf(x1,w6.y,fmaf(x2,w6.z,fmaf(x3,w6.w,lg6))));
        lg7 = fmaf(x0,w7.x,fmaf(x1,w7.y,fmaf(x2,w7.z,fmaf(x3,w7.w,lg7))));
      }
      invn = 1.f / fmaxf(sqrtf(nsq), 1e-12f);
      ls[kg * 8 + 0][px] = lg0 * invn;
      ls[kg * 8 + 1][px] = lg1 * invn;
      ls[kg * 8 + 2][px] = lg2 * invn;
      ls[kg * 8 + 3][px] = lg3 * invn;
      ls[kg * 8 + 4][px] = lg4 * invn;
      ls[kg * 8 + 5][px] = lg5 * invn;
      ls[kg * 8 + 6][px] = lg6 * invn;
      ls[kg * 8 + 7][px] = lg7 * invn;
    }
    __syncthreads();
    // ---- softmax over k (per pixel column; kg-redundant) ----
    {
      const bool valid = (n0 + px) < N_;
      float m = -1e30f;
      for (int k = 0; k < K_; ++k) m = fmaxf(m, ls[k][px]);
      float s = 0.f;
      for (int k = 0; k < K_; ++k) s += __expf(ls[k][px] - m);
      const float sinv = 1.f / s;
      if (own) {
#pragma unroll
        for (int j = 0; j < 8; ++j) {
          const float av = valid ? __expf(ls[kg * 8 + j][px] - m) * sinv : 0.f;
          araw[khbase + j][px] = av;
          a_s[khbase + j][px]  = av * invn;
        }
      }
    }
    __syncthreads();
    // ---- asum update (t<16) + vlad accumulation (all threads) ----
    if (t < 16) {
      float su = 0.f;
#pragma unroll 8
      for (int p = 0; p < PT; ++p) su += araw[t][p];
      asums[t] += su;
    }
    {
#pragma unroll 2
      for (int nl = 0; nl < PT; nl += 2) {
        const ushort2 u0 = ((const ushort2*)xs[nl])[t];
        const ushort2 u1 = ((const ushort2*)xs[nl + 1])[t];
        const float x00 = bf2f(u0.x), x01 = bf2f(u0.y);
        const float x10 = bf2f(u1.x), x11 = bf2f(u1.y);
#pragma unroll
        for (int kh = 0; kh < 16; ++kh) {
          const float2 a2 = *(const float2*)(&a_s[kh][nl]);  // broadcast
          acc[kh * 2]     = fmaf(a2.x, x00, fmaf(a2.y, x10, acc[kh * 2]));
          acc[kh * 2 + 1] = fmaf(a2.x, x01, fmaf(a2.y, x11, acc[kh * 2 + 1]));
        }
      }
    }
    __syncthreads();   // protect xs/a_s/araw from next tile's overwrite
  }

  // ---- epilogue: centroid subtract, row norms, scale (intra * 1/8), store --
  const int d0 = 2 * t;
  const int lane = t & 63, wv = t >> 6;
#pragma unroll
  for (int kh = 0; kh < 16; ++kh) {
    const int k = kq * 16 + kh;
    const float asv = asums[kh];
    const float2 c2 = *(const float2*)(cent + (size_t)k * D_ + d0);
    acc[kh * 2]     -= asv * c2.x;
    acc[kh * 2 + 1] -= asv * c2.y;
    float v = acc[kh * 2] * acc[kh * 2] + acc[kh * 2 + 1] * acc[kh * 2 + 1];
#pragma unroll
    for (int o = 32; o > 0; o >>= 1) v += __shfl_down(v, o, 64);
    if (lane == 0) part[kh][wv] = v;
  }
  __syncthreads();
  if (t < 16) {
    const float s = part[t][0] + part[t][1] + part[t][2] + part[t][3];
    scale_s[t] = 0.125f / fmaxf(sqrtf(s), 1e-12f);  // intra-norm * global 1/sqrt(K)
  }
  __syncthreads();
#pragma unroll
  for (int kh = 0; kh < 16; ++kh) {
    const int k = kq * 16 + kh;
    const float f = scale_s[kh];
    float2 o;
    o.x = acc[kh * 2] * f;
    o.y = acc[kh * 2 + 1] * f;
    *(float2*)(out + ((size_t)b * K_ + k) * D_ + d0) = o;  // fp32, coalesced
  }
}

extern "C" void kernel_launch(void* const* d_in, const int* in_sizes, int n_in,
                              void* d_out, int out_size, void* d_ws, size_t ws_size,
                              hipStream_t stream)
{
  const float* x  = (const float*)d_in[0];   // (B,D,H,W) fp32
  const float* w  = (const float*)d_in[1];   // (K,D) fp32
  const float* ct = (const float*)d_in[2];   // (K,D) fp32
  float* out = (float*)d_out;                // (B, K*D) fp32 (reference dtype)
  (void)d_ws; (void)ws_size;  // zero workspace use

  hipLaunchKernelGGL(k_fused, dim3(256), dim3(256), 0, stream, x, w, ct, out);
}

// Round 6
// 754.602 us; speedup vs baseline: 2.5375x; 2.5375x over previous
//
#include <hip/hip_runtime.h>

#define B_ 64
#define D_ 512
#define N_ 1200
#define K_ 64
#define NT2CNT 19   // ceil(1200/64) pixel tiles for k_logits
#define NT3 16      // n-tile for k_vlad (divides 1200: 75 tiles)
#define PT 32       // fused-fallback pixels per tile
#define NTILES 38   // fused-fallback tiles

__device__ __forceinline__ float bf2f(unsigned short u) {
  union { unsigned int i; float f; } v; v.i = ((unsigned int)u) << 16; return v.f;
}
__device__ __forceinline__ unsigned short f2bf(float f) {
  unsigned int u = __float_as_uint(f);
  u += 0x7FFFu + ((u >> 16) & 1u);   // round-to-nearest-even
  return (unsigned short)(u >> 16);
}

// ---------------- K1: fused L2-norm + logits + softmax -> a(bf16), asum ----
// grid (19, 64), block 256. thread: px = t&63 (pixel), kg = t>>6 (16 k's).
__global__ __launch_bounds__(256) void k_logits(
    const float* __restrict__ x, const float* __restrict__ w,
    unsigned short* __restrict__ a_bf, float* __restrict__ invn_ws,
    float* __restrict__ asum_part)
{
  const int nt = blockIdx.x, b = blockIdx.y;
  const int t = threadIdx.x;
  const int px = t & 63;
  const int kg = t >> 6;            // wave-uniform (w loads scalarize)
  const int n = nt * 64 + px;
  const bool valid = (n < N_);
  const int nc = valid ? n : (N_ - 1);
  __shared__ float ls[K_][65];

  const float* xb = x + (size_t)b * D_ * N_ + nc;
  const float* wg = w + kg * 16 * D_;

  float acc[16];
#pragma unroll
  for (int j = 0; j < 16; ++j) acc[j] = 0.f;
  float nsq = 0.f;

  for (int d = 0; d < D_; d += 4) {
    const float xv0 = xb[(size_t)(d + 0) * N_];   // coalesced over px
    const float xv1 = xb[(size_t)(d + 1) * N_];
    const float xv2 = xb[(size_t)(d + 2) * N_];
    const float xv3 = xb[(size_t)(d + 3) * N_];
    nsq += xv0 * xv0 + xv1 * xv1 + xv2 * xv2 + xv3 * xv3;
#pragma unroll
    for (int j = 0; j < 16; ++j) {
      const float4 wv = *(const float4*)(wg + j * D_ + d);  // wave-uniform
      acc[j] = fmaf(xv0, wv.x, fmaf(xv1, wv.y, fmaf(xv2, wv.z, fmaf(xv3, wv.w, acc[j]))));
    }
  }
  const float invn = 1.f / fmaxf(sqrtf(nsq), 1e-12f);
  if (kg == 0 && valid) invn_ws[b * N_ + n] = invn;
#pragma unroll
  for (int j = 0; j < 16; ++j) ls[kg * 16 + j][px] = acc[j] * invn;
  __syncthreads();
  float m = -1e30f;
  for (int k = 0; k < K_; ++k) m = fmaxf(m, ls[k][px]);
  float s = 0.f;
  for (int k = 0; k < K_; ++k) s += __expf(ls[k][px] - m);
  const float sinv = 1.f / s;
  float av[16];
#pragma unroll
  for (int j = 0; j < 16; ++j)
    av[j] = valid ? __expf(acc[j] * invn - m) * sinv : 0.f;
  __syncthreads();
#pragma unroll
  for (int j = 0; j < 16; ++j) ls[kg * 16 + j][px] = av[j];
  if (valid) {
#pragma unroll
    for (int j = 0; j < 16; ++j)
      a_bf[((size_t)b * K_ + kg * 16 + j) * N_ + n] = f2bf(av[j]);
  }
  __syncthreads();
  if (t < K_) {
    float su = 0.f;
#pragma unroll 8
    for (int p = 0; p < 64; ++p) su += ls[t][p];
    asum_part[(b * NT2CNT + nt) * K_ + t] = su;
  }
}

// ---------------- K2: vlad + intra-norm + global(=1/8) + fp32 out ---------
// grid 512: id = kg*64 + b. thread owns k=kg*8+j x d in {2t,2t+1}.
__global__ __launch_bounds__(256) void k_vlad(
    const float* __restrict__ x, const unsigned short* __restrict__ a_bf,
    const float* __restrict__ invn_ws, const float* __restrict__ asum_part,
    const float* __restrict__ cent, float* __restrict__ out)
{
  const int id = blockIdx.x;
  const int kg = id >> 6;
  const int b  = id & 63;
  const int t  = threadIdx.x;
  __shared__ float xs[NT3][518];
  __shared__ float as[8][NT3 + 2];
  __shared__ float asums[8];
  __shared__ float part[8][4];
  __shared__ float scale_s[8];

  if (t < 8) {
    float s = 0.f;
    for (int nt2 = 0; nt2 < NT2CNT; ++nt2)
      s += asum_part[(b * NT2CNT + nt2) * K_ + kg * 8 + t];
    asums[t] = s;
  }
  float acc[16];
#pragma unroll
  for (int i = 0; i < 16; ++i) acc[i] = 0.f;

  const float* xb = x + (size_t)b * D_ * N_;
  const int d0 = 2 * t;
  const int snl = t & 15, sdc = t >> 4;
  const int saj = t >> 4, sanl = t & 15;

  for (int n0 = 0; n0 < N_; n0 += NT3) {
    __syncthreads();
    {
      const float* xp = xb + (size_t)(sdc * 32) * N_ + (n0 + snl);
      float* xrow = &xs[snl][sdc * 32];
#pragma unroll
      for (int i = 0; i < 32; i += 2) {
        float2 w2;
        w2.x = xp[(size_t)i * N_];
        w2.y = xp[(size_t)(i + 1) * N_];
        *(float2*)(xrow + i) = w2;
      }
    }
    if (t < 128) {
      const float av = bf2f(a_bf[((size_t)b * K_ + kg * 8 + saj) * N_ + n0 + sanl])
                     * invn_ws[b * N_ + n0 + sanl];
      as[saj][sanl] = av;
    }
    __syncthreads();
#pragma unroll 2
    for (int nl = 0; nl < NT3; nl += 2) {
      const float2 x0 = *(const float2*)(&xs[nl][d0]);
      const float2 x1 = *(const float2*)(&xs[nl + 1][d0]);
#pragma unroll
      for (int j = 0; j < 8; ++j) {
        const float2 a2 = *(const float2*)(&as[j][nl]);
        acc[j * 2]     = fmaf(a2.x, x0.x, fmaf(a2.y, x1.x, acc[j * 2]));
        acc[j * 2 + 1] = fmaf(a2.x, x0.y, fmaf(a2.y, x1.y, acc[j * 2 + 1]));
      }
    }
  }
  __syncthreads();
  const int lane = t & 63, wv = t >> 6;
#pragma unroll
  for (int j = 0; j < 8; ++j) {
    const int k = kg * 8 + j;
    const float asv = asums[j];
    const float2 c2 = *(const float2*)(cent + (size_t)k * D_ + d0);
    acc[j * 2]     -= asv * c2.x;
    acc[j * 2 + 1] -= asv * c2.y;
    float v = acc[j * 2] * acc[j * 2] + acc[j * 2 + 1] * acc[j * 2 + 1];
#pragma unroll
    for (int o = 32; o > 0; o >>= 1) v += __shfl_down(v, o, 64);
    if (lane == 0) part[j][wv] = v;
  }
  __syncthreads();
  if (t < 8) {
    const float s = part[t][0] + part[t][1] + part[t][2] + part[t][3];
    scale_s[t] = 0.125f / fmaxf(sqrtf(s), 1e-12f);
  }
  __syncthreads();
#pragma unroll
  for (int j = 0; j < 8; ++j) {
    const int k = kg * 8 + j;
    const float f = scale_s[j];
    float2 o;
    o.x = acc[j * 2] * f;
    o.y = acc[j * 2 + 1] * f;
    *(float2*)(out + ((size_t)b * K_ + k) * D_ + d0) = o;
  }
}

// ---------------- Fallback: round-5 fused zero-workspace kernel -----------
__global__ __launch_bounds__(256) void k_fused(
    const float* __restrict__ x, const float* __restrict__ w,
    const float* __restrict__ cent, float* __restrict__ out)
{
  const int id = blockIdx.x;
  const int kq = id >> 6;
  const int b  = id & 63;
  const int t  = threadIdx.x;
  const int px = t & 31;
  const int kg = t >> 5;
  const bool own = (kg >> 1) == kq;
  const int khbase = (kg & 1) * 8;

  __shared__ unsigned short xs[PT][514];
  __shared__ float ls[K_][33];
  __shared__ float a_s[16][34];
  __shared__ float araw[16][34];
  __shared__ float asums[16];
  __shared__ float part[16][4];
  __shared__ float scale_s[16];

  if (t < 16) asums[t] = 0.f;
  float acc[32];
#pragma unroll
  for (int i = 0; i < 32; ++i) acc[i] = 0.f;
  const float* xb = x + (size_t)b * D_ * N_;

  for (int tile = 0; tile < NTILES; ++tile) {
    const int n0 = tile * PT;
    {
      const int row = t & 31, chunk = t >> 5;
      const int n = n0 + row;
      const int nc = (n < N_) ? n : (N_ - 1);
      const float* xp = xb + (size_t)(chunk * 64) * N_ + nc;
#pragma unroll
      for (int i = 0; i < 64; ++i)
        xs[row][chunk * 64 + i] = f2bf(xp[(size_t)i * N_]);
    }
    __syncthreads();
    float invn;
    {
      const ushort2* xr = (const ushort2*)xs[px];
      float lg[8] = {0,0,0,0,0,0,0,0};
      float nsq = 0.f;
      const float* wbase = w + (size_t)(kg * 8) * D_;
      for (int du = 0; du < D_ / 4; ++du) {
        const ushort2 p0 = xr[2 * du], p1 = xr[2 * du + 1];
        const float x0 = bf2f(p0.x), x1 = bf2f(p0.y), x2 = bf2f(p1.x), x3 = bf2f(p1.y);
        nsq += x0 * x0 + x1 * x1 + x2 * x2 + x3 * x3;
#pragma unroll
        for (int j = 0; j < 8; ++j) {
          const float4 wv = *(const float4*)(wbase + j * D_ + 4 * du);
          lg[j] = fmaf(x0,wv.x,fmaf(x1,wv.y,fmaf(x2,wv.z,fmaf(x3,wv.w,lg[j]))));
        }
      }
      invn = 1.f / fmaxf(sqrtf(nsq), 1e-12f);
#pragma unroll
      for (int j = 0; j < 8; ++j) ls[kg * 8 + j][px] = lg[j] * invn;
    }
    __syncthreads();
    {
      const bool valid = (n0 + px) < N_;
      float m = -1e30f;
      for (int k = 0; k < K_; ++k) m = fmaxf(m, ls[k][px]);
      float s = 0.f;
      for (int k = 0; k < K_; ++k) s += __expf(ls[k][px] - m);
      const float sinv = 1.f / s;
      if (own) {
#pragma unroll
        for (int j = 0; j < 8; ++j) {
          const float av = valid ? __expf(ls[kg * 8 + j][px] - m) * sinv : 0.f;
          araw[khbase + j][px] = av;
          a_s[khbase + j][px]  = av * invn;
        }
      }
    }
    __syncthreads();
    if (t < 16) {
      float su = 0.f;
#pragma unroll 8
      for (int p = 0; p < PT; ++p) su += araw[t][p];
      asums[t] += su;
    }
    {
#pragma unroll 2
      for (int nl = 0; nl < PT; nl += 2) {
        const ushort2 u0 = ((const ushort2*)xs[nl])[t];
        const ushort2 u1 = ((const ushort2*)xs[nl + 1])[t];
        const float x00 = bf2f(u0.x), x01 = bf2f(u0.y);
        const float x10 = bf2f(u1.x), x11 = bf2f(u1.y);
#pragma unroll
        for (int kh = 0; kh < 16; ++kh) {
          const float2 a2 = *(const float2*)(&a_s[kh][nl]);
          acc[kh * 2]     = fmaf(a2.x, x00, fmaf(a2.y, x10, acc[kh * 2]));
          acc[kh * 2 + 1] = fmaf(a2.x, x01, fmaf(a2.y, x11, acc[kh * 2 + 1]));
        }
      }
    }
    __syncthreads();
  }
  const int d0 = 2 * t;
  const int lane = t & 63, wv = t >> 6;
#pragma unroll
  for (int kh = 0; kh < 16; ++kh) {
    const int k = kq * 16 + kh;
    const float asv = asums[kh];
    const float2 c2 = *(const float2*)(cent + (size_t)k * D_ + d0);
    acc[kh * 2]     -= asv * c2.x;
    acc[kh * 2 + 1] -= asv * c2.y;
    float v = acc[kh * 2] * acc[kh * 2] + acc[kh * 2 + 1] * acc[kh * 2 + 1];
#pragma unroll
    for (int o = 32; o > 0; o >>= 1) v += __shfl_down(v, o, 64);
    if (lane == 0) part[kh][wv] = v;
  }
  __syncthreads();
  if (t < 16) {
    const float s = part[t][0] + part[t][1] + part[t][2] + part[t][3];
    scale_s[t] = 0.125f / fmaxf(sqrtf(s), 1e-12f);
  }
  __syncthreads();
#pragma unroll
  for (int kh = 0; kh < 16; ++kh) {
    const int k = kq * 16 + kh;
    const float f = scale_s[kh];
    float2 o;
    o.x = acc[kh * 2] * f;
    o.y = acc[kh * 2 + 1] * f;
    *(float2*)(out + ((size_t)b * K_ + k) * D_ + d0) = o;
  }
}

extern "C" void kernel_launch(void* const* d_in, const int* in_sizes, int n_in,
                              void* d_out, int out_size, void* d_ws, size_t ws_size,
                              hipStream_t stream)
{
  const float* x  = (const float*)d_in[0];   // (B,D,H,W) fp32
  const float* w  = (const float*)d_in[1];   // (K,D) fp32
  const float* ct = (const float*)d_in[2];   // (K,D) fp32
  float* out = (float*)d_out;                // (B, K*D) fp32

  const size_t invn_f  = (size_t)B_ * N_;            // 76,800 floats
  const size_t asum_f  = (size_t)B_ * NT2CNT * K_;   // 77,824 floats
  const size_t a_u16   = (size_t)B_ * K_ * N_;       // 4,915,200 ushorts
  const size_t need = (invn_f + asum_f) * 4 + a_u16 * 2;  // ~10.4 MB

  if (ws_size >= need) {
    float* invn_ws   = (float*)d_ws;
    float* asum_part = invn_ws + invn_f;
    unsigned short* a_bf = (unsigned short*)(asum_part + asum_f);
    hipLaunchKernelGGL(k_logits, dim3(NT2CNT, B_), dim3(256), 0, stream,
                       x, w, a_bf, invn_ws, asum_part);
    hipLaunchKernelGGL(k_vlad, dim3(512), dim3(256), 0, stream,
                       x, a_bf, invn_ws, asum_part, ct, out);
  } else {
    hipLaunchKernelGGL(k_fused, dim3(256), dim3(256), 0, stream, x, w, ct, out);
  }
}